// Round 4
// baseline (1238.778 us; speedup 1.0000x reference)
//
#include <hip/hip_runtime.h>
#include <hip/hip_bf16.h>
#include <cstdint>

#define B_   8
#define N_   512
#define HID_ 512
#define H_   8
#define D_   64
#define E_   32

typedef unsigned short u16;
typedef unsigned int   u32;
typedef float  float4_t __attribute__((ext_vector_type(4)));
typedef u32    uint4v   __attribute__((ext_vector_type(4)));
typedef __bf16 bf16x8   __attribute__((ext_vector_type(8)));

__device__ __forceinline__ float b2f(u16 u) {
    return __uint_as_float(((u32)u) << 16);
}
__device__ __forceinline__ u16 f2b(float f) {
    u32 b = __float_as_uint(f);
    b += 0x7fffu + ((b >> 16) & 1u);   // RNE
    return (u16)(b >> 16);
}
__device__ __forceinline__ u32 pk2(float a, float b) {
    return (u32)f2b(a) | ((u32)f2b(b) << 16);
}
__device__ __forceinline__ void unp8(uint4v u, float* f) {
    f[0] = __uint_as_float(u[0] << 16); f[1] = __uint_as_float(u[0] & 0xffff0000u);
    f[2] = __uint_as_float(u[1] << 16); f[3] = __uint_as_float(u[1] & 0xffff0000u);
    f[4] = __uint_as_float(u[2] << 16); f[5] = __uint_as_float(u[2] & 0xffff0000u);
    f[6] = __uint_as_float(u[3] << 16); f[7] = __uint_as_float(u[3] & 0xffff0000u);
}

// ---------------------------------------------------------------------------
// GEMM (bf16 MFMA, fp32 accum): out[M=4096, n] = X[4096,512] @ W[512,n] + bias
// kind==0: X fp32, fused QKV, grid.y=24 (0-7 -> q fp32, 8-15 -> k(+ct_key) bf16,
//          16-23 -> v bf16)
// kind==1: X bf16 (attn out in ws), O-projection, grid.y=8, writes fp32 d_out
// Tile: 128 x 64, K-step 32. 4 waves; wave w -> rows [w*32, w*32+32), 64 cols.
// ---------------------------------------------------------------------------
__global__ __launch_bounds__(256) void gemm_kernel(
    const float* __restrict__ Xf, const u16* __restrict__ Xb,
    const float* __restrict__ W0, const float* __restrict__ W1, const float* __restrict__ W2,
    const float* __restrict__ Bq, const float* __restrict__ Bk, const float* __restrict__ Bv,
    float* __restrict__ qout, u16* __restrict__ kout, u16* __restrict__ vout,
    float* __restrict__ fout,
    const float* __restrict__ ctk, const int* __restrict__ ct, int kind)
{
    __shared__ u16 lx[128 * 40];   // [m][k] bf16, stride 40 (80B rows, 16B aligned)
    __shared__ u16 lw[64 * 40];    // [n][k] bf16 (W transposed), stride 40

    const int t  = threadIdx.x;
    const int m0 = blockIdx.x * 128;
    const int n0g = blockIdx.y * 64;

    int mode, cl0;
    const float* W; const float* Bi;
    if (kind == 0) {
        mode = n0g >> 9; cl0 = n0g & 511;
        W  = (mode == 0) ? W0 : ((mode == 1) ? W1 : W2);
        Bi = (mode == 0) ? Bq : ((mode == 1) ? Bk : Bv);
    } else {
        mode = 3; cl0 = n0g; W = W0; Bi = Bq;
    }

    const int wv = t >> 6, lane = t & 63, quad = lane >> 4, l16 = lane & 15;

    float4_t acc[2][4];
    #pragma unroll
    for (int mi = 0; mi < 2; ++mi)
        #pragma unroll
        for (int ni = 0; ni < 4; ++ni) {
            float4_t z = {0.f, 0.f, 0.f, 0.f};
            acc[mi][ni] = z;
        }

    for (int k0 = 0; k0 < 512; k0 += 32) {
        // stage X tile: 128 rows x 32 k; 512 chunks of 8 elems; thread does 2
        if (kind == 0) {
            #pragma unroll
            for (int half = 0; half < 2; ++half) {
                const int c = t + half * 256;
                const int r = c >> 2, ck = c & 3;
                const float* src = &Xf[(m0 + r) * 512 + k0 + ck * 8];
                float4_t a0 = *(const float4_t*)src;
                float4_t a1 = *(const float4_t*)(src + 4);
                uint4v p;
                p[0] = pk2(a0[0], a0[1]); p[1] = pk2(a0[2], a0[3]);
                p[2] = pk2(a1[0], a1[1]); p[3] = pk2(a1[2], a1[3]);
                *(uint4v*)&lx[r * 40 + ck * 8] = p;
            }
        } else {
            #pragma unroll
            for (int half = 0; half < 2; ++half) {
                const int c = t + half * 256;
                const int r = c >> 2, ck = c & 3;
                *(uint4v*)&lx[r * 40 + ck * 8] =
                    *(const uint4v*)&Xb[(m0 + r) * 512 + k0 + ck * 8];
            }
        }
        // stage W tile transposed: 32 k x 64 n (fp32 -> bf16)
        {
            const int kl = t >> 3, nc = t & 7;
            const float* src = &W[(k0 + kl) * 512 + cl0 + nc * 8];
            float4_t wa = *(const float4_t*)src;
            float4_t wb = *(const float4_t*)(src + 4);
            lw[(nc * 8 + 0) * 40 + kl] = f2b(wa[0]);
            lw[(nc * 8 + 1) * 40 + kl] = f2b(wa[1]);
            lw[(nc * 8 + 2) * 40 + kl] = f2b(wa[2]);
            lw[(nc * 8 + 3) * 40 + kl] = f2b(wa[3]);
            lw[(nc * 8 + 4) * 40 + kl] = f2b(wb[0]);
            lw[(nc * 8 + 5) * 40 + kl] = f2b(wb[1]);
            lw[(nc * 8 + 6) * 40 + kl] = f2b(wb[2]);
            lw[(nc * 8 + 7) * 40 + kl] = f2b(wb[3]);
        }
        __syncthreads();

        bf16x8 af[2], bfr[4];
        af[0] = *(bf16x8*)&lx[(wv * 32 +      l16) * 40 + quad * 8];
        af[1] = *(bf16x8*)&lx[(wv * 32 + 16 + l16) * 40 + quad * 8];
        #pragma unroll
        for (int ni = 0; ni < 4; ++ni)
            bfr[ni] = *(bf16x8*)&lw[(ni * 16 + l16) * 40 + quad * 8];

        #pragma unroll
        for (int mi = 0; mi < 2; ++mi)
            #pragma unroll
            for (int ni = 0; ni < 4; ++ni)
                acc[mi][ni] = __builtin_amdgcn_mfma_f32_16x16x32_bf16(af[mi], bfr[ni], acc[mi][ni], 0, 0, 0);
        __syncthreads();
    }

    // epilogue
    const int b_blk = m0 >> 9;   // 128-row block never straddles a batch (512 rows)
    #pragma unroll
    for (int ni = 0; ni < 4; ++ni) {
        const int cl = cl0 + ni * 16 + l16;
        const float bias = Bi[cl];
        float ctkv = 0.f;
        if (mode == 1) ctkv = ctk[ct[b_blk] * HID_ + cl];
        #pragma unroll
        for (int mi = 0; mi < 2; ++mi) {
            #pragma unroll
            for (int reg = 0; reg < 4; ++reg) {
                const int gm = m0 + wv * 32 + mi * 16 + quad * 4 + reg;
                float val = acc[mi][ni][reg] + bias;
                if (mode == 0)      qout[gm * 512 + cl] = val * 0.125f;     // fold 1/sqrt(D)
                else if (mode == 1) kout[gm * 512 + cl] = f2b(val + ctkv);
                else if (mode == 2) vout[gm * 512 + cl] = f2b(val);
                else                fout[gm * 512 + cl] = val;
            }
        }
    }
}

// ---------------------------------------------------------------------------
// Fused attention: one block per (b, 2 query rows), all 8 heads.
// Edge MLP computed in-kernel (fp32 weights staged in LDS). logits ->
// LDS S[2][8][512] -> softmax (Z==0 => row 0, matches nan_to_num) ->
// attn_mean (fp32, d_out part 2) -> PV -> attn_out (bf16 ws).
// ---------------------------------------------------------------------------
__global__ __launch_bounds__(256) void attn_kernel(
    const float* __restrict__ qws, const u16* __restrict__ kws, const u16* __restrict__ vws,
    const float* __restrict__ ef,
    const float* __restrict__ We1, const float* __restrict__ be1,
    const float* __restrict__ We2, const float* __restrict__ be2,
    const int* __restrict__ bmask, const int* __restrict__ pmask,
    u16* __restrict__ attn_out, float* __restrict__ mean_out)
{
    __shared__ float ql[2 * 512];
    __shared__ float S[2][8][512];
    __shared__ __align__(16) float wf[2632];   // We1[32][64] | be1[64] | We2[64][8] | be2[8]

    const int t = threadIdx.x;
    const int b = blockIdx.x >> 8;            // 256 blocks per batch
    const int i0 = (blockIdx.x & 255) * 2;
    const int row0 = b * N_ + i0;

    // stage edge-MLP weights (fp32 in LDS)
    for (int i = t; i < 2632; i += 256) {
        float v;
        if (i < 2048)      v = We1[i];
        else if (i < 2112) v = be1[i - 2048];
        else if (i < 2624) v = We2[i - 2112];
        else               v = be2[i - 2624];
        wf[i] = v;
    }
    // load 2 q rows (pre-scaled fp32)
    *(float4_t*)&ql[t * 4] = *(const float4_t*)&qws[row0 * 512 + t * 4];

    const int padi0 = pmask[b * N_ + i0];
    const int padi1 = pmask[b * N_ + i0 + 1];
    __syncthreads();

    const float4_t* We1v = (const float4_t*)wf;            // [e][o4], 512 entries
    const float4_t* be1v = (const float4_t*)(wf + 2048);   // 16 entries
    const float4_t* We2v = (const float4_t*)(wf + 2112);   // [o][p4], 128 entries
    const float4_t* be2v = (const float4_t*)(wf + 2624);   // 2 entries

    // ---- logits (edge MLP fused) ----
    for (int jj = t; jj < 512; jj += 256) {
        const int pj  = pmask[b * N_ + jj];
        const int bm0 = bmask[row0 * 512 + jj];
        const int bm1 = bmask[(row0 + 1) * 512 + jj];
        const bool msk0 = (padi0 | pj | bm0) != 0;
        const bool msk1 = (padi1 | pj | bm1) != 0;

        // edge features for the 2 rows (fp32)
        float x0[32], x1[32];
        {
            const float4_t* p0 = (const float4_t*)(ef + ((long)row0       * 512 + jj) * 32);
            const float4_t* p1 = (const float4_t*)(ef + ((long)(row0 + 1) * 512 + jj) * 32);
            #pragma unroll
            for (int c = 0; c < 8; ++c) {
                float4_t a = p0[c], bb = p1[c];
                #pragma unroll
                for (int z = 0; z < 4; ++z) { x0[c * 4 + z] = a[z]; x1[c * 4 + z] = bb[z]; }
            }
        }

        // edge MLP: layer1 chunk of 4 hidden units at a time, elu, layer2
        float e0[8], e1[8];
        {
            float4_t o0a = be2v[0], o0b = be2v[1];
            float4_t o1a = o0a,     o1b = o0b;
            #pragma unroll 1
            for (int o4 = 0; o4 < 16; ++o4) {
                float4_t h0 = be1v[o4], h1 = h0;
                #pragma unroll
                for (int e = 0; e < 32; ++e) {
                    const float4_t w = We1v[e * 16 + o4];
                    const float xe0 = x0[e], xe1 = x1[e];
                    #pragma unroll
                    for (int z = 0; z < 4; ++z) {
                        h0[z] = fmaf(xe0, w[z], h0[z]);
                        h1[z] = fmaf(xe1, w[z], h1[z]);
                    }
                }
                #pragma unroll
                for (int z = 0; z < 4; ++z) {
                    h0[z] = (h0[z] > 0.f) ? h0[z] : expm1f(h0[z]);
                    h1[z] = (h1[z] > 0.f) ? h1[z] : expm1f(h1[z]);
                }
                #pragma unroll
                for (int z = 0; z < 4; ++z) {
                    const int o = o4 * 4 + z;
                    const float4_t wa = We2v[o * 2], wb = We2v[o * 2 + 1];
                    #pragma unroll
                    for (int p = 0; p < 4; ++p) {
                        o0a[p] = fmaf(h0[z], wa[p], o0a[p]);
                        o0b[p] = fmaf(h0[z], wb[p], o0b[p]);
                        o1a[p] = fmaf(h1[z], wa[p], o1a[p]);
                        o1b[p] = fmaf(h1[z], wb[p], o1b[p]);
                    }
                }
            }
            #pragma unroll
            for (int p = 0; p < 4; ++p) {
                e0[p] = o0a[p]; e0[p + 4] = o0b[p];
                e1[p] = o1a[p]; e1[p + 4] = o1b[p];
            }
        }

        const u16* kp = kws + (long)(b * N_ + jj) * 512;
        #pragma unroll
        for (int h = 0; h < 8; ++h) {
            float d0 = 0.f, d1 = 0.f;
            #pragma unroll
            for (int c = 0; c < 8; ++c) {
                uint4v u = *(const uint4v*)(kp + h * 64 + c * 8);
                float kf[8]; unp8(u, kf);
                const float* q0 = &ql[h * 64 + c * 8];
                const float* q1 = &ql[512 + h * 64 + c * 8];
                #pragma unroll
                for (int z = 0; z < 8; ++z) {
                    d0 = fmaf(kf[z], q0[z], d0);
                    d1 = fmaf(kf[z], q1[z], d1);
                }
            }
            S[0][h][jj] = msk0 ? -__builtin_inff() : (d0 + e0[h]);
            S[1][h][jj] = msk1 ? -__builtin_inff() : (d1 + e1[h]);
        }
    }
    __syncthreads();

    // ---- softmax per (row, head): 8 groups of 32 lanes, one head each ----
    {
        const int h = t >> 5, l = t & 31;
        #pragma unroll
        for (int r = 0; r < 2; ++r) {
            float m = -__builtin_inff();
            for (int kk = 0; kk < 16; ++kk) m = fmaxf(m, S[r][h][l + 32 * kk]);
            #pragma unroll
            for (int off = 16; off >= 1; off >>= 1) m = fmaxf(m, __shfl_xor(m, off, 32));

            float zsum = 0.f;
            for (int kk = 0; kk < 16; ++kk) {
                const int j = l + 32 * kk;
                const float s = S[r][h][j];
                const float e = (s == -__builtin_inff()) ? 0.f : __expf(s - m);
                S[r][h][j] = e;
                zsum += e;
            }
            #pragma unroll
            for (int off = 16; off >= 1; off >>= 1) zsum += __shfl_xor(zsum, off, 32);

            const float inv = (zsum > 0.f) ? (1.f / zsum) : 0.f;
            for (int kk = 0; kk < 16; ++kk) S[r][h][l + 32 * kk] *= inv;
        }
    }
    __syncthreads();

    // ---- attn mean over heads (output 1, fp32) ----
    for (int jj = t; jj < 512; jj += 256) {
        #pragma unroll
        for (int r = 0; r < 2; ++r) {
            float sum = 0.f;
            #pragma unroll
            for (int h = 0; h < 8; ++h) sum += S[r][h][jj];
            mean_out[(long)(row0 + r) * 512 + jj] = sum * 0.125f;
        }
    }

    // ---- PV: thread -> (head, 2 dims), v load shared across the 2 rows ----
    {
        const int h = t >> 5, d0 = (t & 31) * 2;
        float a00 = 0.f, a01 = 0.f, a10 = 0.f, a11 = 0.f;
        const u16* vp = vws + (long)(b * N_) * 512 + h * 64 + d0;
        #pragma unroll 4
        for (int j = 0; j < 512; ++j) {
            const u32 u = *(const u32*)(vp + (long)j * 512);
            const float v0 = __uint_as_float(u << 16);
            const float v1 = __uint_as_float(u & 0xffff0000u);
            const float p0 = S[0][h][j];
            const float p1 = S[1][h][j];
            a00 = fmaf(p0, v0, a00); a01 = fmaf(p0, v1, a01);
            a10 = fmaf(p1, v0, a10); a11 = fmaf(p1, v1, a11);
        }
        *(u32*)&attn_out[(long)row0       * 512 + h * 64 + d0] = pk2(a00, a01);
        *(u32*)&attn_out[(long)(row0 + 1) * 512 + h * 64 + d0] = pk2(a10, a11);
    }
}

// ---------------------------------------------------------------------------
extern "C" void kernel_launch(void* const* d_in, const int* in_sizes, int n_in,
                              void* d_out, int out_size, void* d_ws, size_t ws_size,
                              hipStream_t stream) {
    const float* x   = (const float*)d_in[0];
    const int*   ct  = (const int*)d_in[1];
    const float* ef  = (const float*)d_in[2];
    const int*   bm  = (const int*)d_in[3];
    const int*   pm  = (const int*)d_in[4];
    const float* Wq  = (const float*)d_in[5];  const float* bq = (const float*)d_in[6];
    const float* Wk  = (const float*)d_in[7];  const float* bk = (const float*)d_in[8];
    const float* Wv  = (const float*)d_in[9];  const float* bv = (const float*)d_in[10];
    const float* Wo  = (const float*)d_in[11]; const float* bo = (const float*)d_in[12];
    const float* We1 = (const float*)d_in[13]; const float* be1 = (const float*)d_in[14];
    const float* We2 = (const float*)d_in[15]; const float* be2 = (const float*)d_in[16];
    const float* ctk = (const float*)d_in[17];
    // d_in[18] = ct_bias_emb: constant along softmax axis -> cancels; unused.

    char* ws = (char*)d_ws;
    float* qws  = (float*)ws;                    //  8,388,608 B (fp32, pre-scaled)
    u16*   kws  = (u16*)(ws + 8388608);          //  4,194,304 B (bf16, +ct_key)
    u16*   vws  = (u16*)(ws + 12582912);         //  4,194,304 B
    u16*   aout = (u16*)(ws + 16777216);         //  4,194,304 B (attn out, bf16)
    // total ws usage: 20,971,520 B

    float* out0 = (float*)d_out;        // (B,N,HID) fp32
    float* out1 = out0 + 2097152;       // (B,N,N)  fp32 attn mean

    gemm_kernel<<<dim3(32, 24), 256, 0, stream>>>(x, nullptr, Wq, Wk, Wv, bq, bk, bv,
                                                  qws, kws, vws, out0, ctk, ct, 0);
    attn_kernel<<<2048, 256, 0, stream>>>(qws, kws, vws, ef, We1, be1, We2, be2,
                                          bm, pm, aout, out1);
    gemm_kernel<<<dim3(32, 8), 256, 0, stream>>>(nullptr, aout, Wo, Wo, Wo, bo, bo, bo,
                                                 qws, kws, vws, out0, ctk, ct, 1);
}

// Round 5
// 918.455 us; speedup vs baseline: 1.3488x; 1.3488x over previous
//
#include <hip/hip_runtime.h>
#include <hip/hip_bf16.h>
#include <cstdint>

#define B_   8
#define N_   512
#define HID_ 512
#define H_   8
#define D_   64
#define E_   32

typedef unsigned short u16;
typedef unsigned int   u32;
typedef float  float4_t __attribute__((ext_vector_type(4)));
typedef u32    uint4v   __attribute__((ext_vector_type(4)));
typedef __bf16 bf16x8   __attribute__((ext_vector_type(8)));

__device__ __forceinline__ float b2f(u16 u) {
    return __uint_as_float(((u32)u) << 16);
}
__device__ __forceinline__ u16 f2b(float f) {
    u32 b = __float_as_uint(f);
    b += 0x7fffu + ((b >> 16) & 1u);   // RNE
    return (u16)(b >> 16);
}
__device__ __forceinline__ u32 pk2(float a, float b) {
    return (u32)f2b(a) | ((u32)f2b(b) << 16);
}
__device__ __forceinline__ void unp8(uint4v u, float* f) {
    f[0] = __uint_as_float(u[0] << 16); f[1] = __uint_as_float(u[0] & 0xffff0000u);
    f[2] = __uint_as_float(u[1] << 16); f[3] = __uint_as_float(u[1] & 0xffff0000u);
    f[4] = __uint_as_float(u[2] << 16); f[5] = __uint_as_float(u[2] & 0xffff0000u);
    f[6] = __uint_as_float(u[3] << 16); f[7] = __uint_as_float(u[3] & 0xffff0000u);
}

// ---------------------------------------------------------------------------
// GEMM (bf16 MFMA, fp32 accum): out[M=4096, n] = X[4096,512] @ W[512,n] + bias
// kind==0: X fp32, fused QKV, grid.y=24 (0-7 -> q fp32, 8-15 -> k(+ct_key) bf16,
//          16-23 -> v bf16)
// kind==1: X bf16 (attn out in ws), O-projection, grid.y=8, writes fp32 d_out
// ---------------------------------------------------------------------------
__global__ __launch_bounds__(256) void gemm_kernel(
    const float* __restrict__ Xf, const u16* __restrict__ Xb,
    const float* __restrict__ W0, const float* __restrict__ W1, const float* __restrict__ W2,
    const float* __restrict__ Bq, const float* __restrict__ Bk, const float* __restrict__ Bv,
    float* __restrict__ qout, u16* __restrict__ kout, u16* __restrict__ vout,
    float* __restrict__ fout,
    const float* __restrict__ ctk, const int* __restrict__ ct, int kind)
{
    __shared__ u16 lx[128 * 40];   // [m][k] bf16, stride 40 (80B rows, 16B aligned)
    __shared__ u16 lw[64 * 40];    // [n][k] bf16 (W transposed), stride 40

    const int t  = threadIdx.x;
    const int m0 = blockIdx.x * 128;
    const int n0g = blockIdx.y * 64;

    int mode, cl0;
    const float* W; const float* Bi;
    if (kind == 0) {
        mode = n0g >> 9; cl0 = n0g & 511;
        W  = (mode == 0) ? W0 : ((mode == 1) ? W1 : W2);
        Bi = (mode == 0) ? Bq : ((mode == 1) ? Bk : Bv);
    } else {
        mode = 3; cl0 = n0g; W = W0; Bi = Bq;
    }

    const int wv = t >> 6, lane = t & 63, quad = lane >> 4, l16 = lane & 15;

    float4_t acc[2][4];
    #pragma unroll
    for (int mi = 0; mi < 2; ++mi)
        #pragma unroll
        for (int ni = 0; ni < 4; ++ni) {
            float4_t z = {0.f, 0.f, 0.f, 0.f};
            acc[mi][ni] = z;
        }

    for (int k0 = 0; k0 < 512; k0 += 32) {
        if (kind == 0) {
            #pragma unroll
            for (int half = 0; half < 2; ++half) {
                const int c = t + half * 256;
                const int r = c >> 2, ck = c & 3;
                const float* src = &Xf[(m0 + r) * 512 + k0 + ck * 8];
                float4_t a0 = *(const float4_t*)src;
                float4_t a1 = *(const float4_t*)(src + 4);
                uint4v p;
                p[0] = pk2(a0[0], a0[1]); p[1] = pk2(a0[2], a0[3]);
                p[2] = pk2(a1[0], a1[1]); p[3] = pk2(a1[2], a1[3]);
                *(uint4v*)&lx[r * 40 + ck * 8] = p;
            }
        } else {
            #pragma unroll
            for (int half = 0; half < 2; ++half) {
                const int c = t + half * 256;
                const int r = c >> 2, ck = c & 3;
                *(uint4v*)&lx[r * 40 + ck * 8] =
                    *(const uint4v*)&Xb[(m0 + r) * 512 + k0 + ck * 8];
            }
        }
        {
            const int kl = t >> 3, nc = t & 7;
            const float* src = &W[(k0 + kl) * 512 + cl0 + nc * 8];
            float4_t wa = *(const float4_t*)src;
            float4_t wb = *(const float4_t*)(src + 4);
            lw[(nc * 8 + 0) * 40 + kl] = f2b(wa[0]);
            lw[(nc * 8 + 1) * 40 + kl] = f2b(wa[1]);
            lw[(nc * 8 + 2) * 40 + kl] = f2b(wa[2]);
            lw[(nc * 8 + 3) * 40 + kl] = f2b(wa[3]);
            lw[(nc * 8 + 4) * 40 + kl] = f2b(wb[0]);
            lw[(nc * 8 + 5) * 40 + kl] = f2b(wb[1]);
            lw[(nc * 8 + 6) * 40 + kl] = f2b(wb[2]);
            lw[(nc * 8 + 7) * 40 + kl] = f2b(wb[3]);
        }
        __syncthreads();

        bf16x8 af[2], bfr[4];
        af[0] = *(bf16x8*)&lx[(wv * 32 +      l16) * 40 + quad * 8];
        af[1] = *(bf16x8*)&lx[(wv * 32 + 16 + l16) * 40 + quad * 8];
        #pragma unroll
        for (int ni = 0; ni < 4; ++ni)
            bfr[ni] = *(bf16x8*)&lw[(ni * 16 + l16) * 40 + quad * 8];

        #pragma unroll
        for (int mi = 0; mi < 2; ++mi)
            #pragma unroll
            for (int ni = 0; ni < 4; ++ni)
                acc[mi][ni] = __builtin_amdgcn_mfma_f32_16x16x32_bf16(af[mi], bfr[ni], acc[mi][ni], 0, 0, 0);
        __syncthreads();
    }

    const int b_blk = m0 >> 9;
    #pragma unroll
    for (int ni = 0; ni < 4; ++ni) {
        const int cl = cl0 + ni * 16 + l16;
        const float bias = Bi[cl];
        float ctkv = 0.f;
        if (mode == 1) ctkv = ctk[ct[b_blk] * HID_ + cl];
        #pragma unroll
        for (int mi = 0; mi < 2; ++mi) {
            #pragma unroll
            for (int reg = 0; reg < 4; ++reg) {
                const int gm = m0 + wv * 32 + mi * 16 + quad * 4 + reg;
                float val = acc[mi][ni][reg] + bias;
                if (mode == 0)      qout[gm * 512 + cl] = val * 0.125f;
                else if (mode == 1) kout[gm * 512 + cl] = f2b(val + ctkv);
                else if (mode == 2) vout[gm * 512 + cl] = f2b(val);
                else                fout[gm * 512 + cl] = val;
            }
        }
    }
}

// ---------------------------------------------------------------------------
// Edge MLP via MFMA: eb[p,h] = elu(ef[p,:]@We1+be1)@We2+be2, p in [0,2M).
// Layer1: K=32 == one 16x16x32 MFMA K. Fragment layouts identical to the
// HW-verified gemm_kernel above (A: m=l16,k=quad*8+j; B: n=l16(+16ni); C/D:
// col=l16, row=quad*4+reg). Layer2 (K=64): H1 round-trips through a per-wave
// private LDS tile to convert C-layout -> A-layout.
// Block: 4 waves x 16 rows x 4 tiles = 256 pair-rows; grid 8192.
// ---------------------------------------------------------------------------
__global__ __launch_bounds__(256) void edge_kernel(
    const float* __restrict__ ef,
    const float* __restrict__ We1, const float* __restrict__ be1,
    const float* __restrict__ We2, const float* __restrict__ be2,
    u16* __restrict__ eb)
{
    __shared__ u16 lw1[64 * 32];       // B1[n=hidden][k=e]  (We1 transposed)
    __shared__ u16 lw2[16 * 64];       // B2[n=out(8 valid)][k=hidden] (We2^T, padded)
    __shared__ u16 h1t[4][16 * 72];    // per-wave H1 tile [row][k], stride 72 (144B, 16B-aligned)

    const int t = threadIdx.x;
    const int wv = t >> 6, lane = t & 63, quad = lane >> 4, l16 = lane & 15;

    for (int i = t; i < 2048; i += 256) {
        const int n = i >> 5, k = i & 31;
        lw1[n * 32 + k] = f2b(We1[k * 64 + n]);
    }
    for (int i = t; i < 1024; i += 256) {
        const int n = i >> 6, k = i & 63;
        lw2[n * 64 + k] = (n < 8) ? f2b(We2[k * 8 + n]) : (u16)0;
    }
    __syncthreads();

    bf16x8 b1[4];
    #pragma unroll
    for (int ni = 0; ni < 4; ++ni)
        b1[ni] = *(bf16x8*)&lw1[(ni * 16 + l16) * 32 + quad * 8];
    bf16x8 b20 = *(bf16x8*)&lw2[l16 * 64 +      quad * 8];
    bf16x8 b21 = *(bf16x8*)&lw2[l16 * 64 + 32 + quad * 8];

    float be1r[4];
    #pragma unroll
    for (int ni = 0; ni < 4; ++ni) be1r[ni] = be1[l16 + 16 * ni];
    const float be2r = (l16 < 8) ? be2[l16] : 0.f;

    for (int tt = 0; tt < 4; ++tt) {
        const long row0g = (long)blockIdx.x * 256 + tt * 64 + wv * 16;

        // A1 frag straight from global (coalesced dwordx4), fp32 -> bf16
        const float* ap = ef + (row0g + l16) * 32 + quad * 8;
        float4_t f0 = *(const float4_t*)ap;
        float4_t f1 = *(const float4_t*)(ap + 4);
        uint4v au;
        au[0] = pk2(f0[0], f0[1]); au[1] = pk2(f0[2], f0[3]);
        au[2] = pk2(f1[0], f1[1]); au[3] = pk2(f1[2], f1[3]);
        bf16x8 a1 = *(bf16x8*)&au;

        float4_t zero = {0.f, 0.f, 0.f, 0.f};
        float4_t c1[4];
        #pragma unroll
        for (int ni = 0; ni < 4; ++ni)
            c1[ni] = __builtin_amdgcn_mfma_f32_16x16x32_bf16(a1, b1[ni], zero, 0, 0, 0);

        // bias + ELU, write H1 tile (own-wave private region)
        #pragma unroll
        for (int ni = 0; ni < 4; ++ni) {
            #pragma unroll
            for (int reg = 0; reg < 4; ++reg) {
                float v = c1[ni][reg] + be1r[ni];
                v = (v > 0.f) ? v : expm1f(v);
                h1t[wv][(quad * 4 + reg) * 72 + l16 + 16 * ni] = f2b(v);
            }
        }
        __syncthreads();

        // Layer2: A2 from H1 tile (A-layout), two K=32 MFMAs
        bf16x8 a20 = *(bf16x8*)&h1t[wv][l16 * 72 +      quad * 8];
        bf16x8 a21 = *(bf16x8*)&h1t[wv][l16 * 72 + 32 + quad * 8];
        float4_t c2 = zero;
        c2 = __builtin_amdgcn_mfma_f32_16x16x32_bf16(a20, b20, c2, 0, 0, 0);
        c2 = __builtin_amdgcn_mfma_f32_16x16x32_bf16(a21, b21, c2, 0, 0, 0);

        if (l16 < 8) {
            #pragma unroll
            for (int reg = 0; reg < 4; ++reg)
                eb[(row0g + quad * 4 + reg) * 8 + l16] = f2b(c2[reg] + be2r);
        }
        __syncthreads();
    }
}

// ---------------------------------------------------------------------------
// Attention v2 (edge MLP precomputed): one block per (b, 2 query rows).
// logits -> LDS S[2][8][512] -> softmax (Z==0 => row 0) -> attn_mean (fp32)
// -> PV -> attn_out (bf16 ws).
// ---------------------------------------------------------------------------
__global__ __launch_bounds__(256, 4) void attn_kernel(
    const float* __restrict__ qws, const u16* __restrict__ kws, const u16* __restrict__ vws,
    const u16* __restrict__ ebws,
    const int* __restrict__ bmask, const int* __restrict__ pmask,
    u16* __restrict__ attn_out, float* __restrict__ mean_out)
{
    __shared__ float ql[2 * 512];
    __shared__ float S[2][8][512];

    const int t = threadIdx.x;
    const int b = blockIdx.x >> 8;
    const int i0 = (blockIdx.x & 255) * 2;
    const int row0 = b * N_ + i0;

    *(float4_t*)&ql[t * 4] = *(const float4_t*)&qws[row0 * 512 + t * 4];

    const int padi0 = pmask[b * N_ + i0];
    const int padi1 = pmask[b * N_ + i0 + 1];
    __syncthreads();

    // ---- logits ----
    for (int jj = t; jj < 512; jj += 256) {
        const int pj  = pmask[b * N_ + jj];
        const int bm0 = bmask[row0 * 512 + jj];
        const int bm1 = bmask[(row0 + 1) * 512 + jj];
        const bool msk0 = (padi0 | pj | bm0) != 0;
        const bool msk1 = (padi1 | pj | bm1) != 0;

        float e0[8], e1[8];
        { uint4v u = *(const uint4v*)(ebws + ((long)row0       * 512 + jj) * 8); unp8(u, e0); }
        { uint4v u = *(const uint4v*)(ebws + ((long)(row0 + 1) * 512 + jj) * 8); unp8(u, e1); }

        const u16* kp = kws + (long)(b * N_ + jj) * 512;
        #pragma unroll
        for (int h = 0; h < 8; ++h) {
            float d0 = 0.f, d1 = 0.f;
            #pragma unroll
            for (int c = 0; c < 8; ++c) {
                uint4v u = *(const uint4v*)(kp + h * 64 + c * 8);
                float kf[8]; unp8(u, kf);
                const float* q0 = &ql[h * 64 + c * 8];
                const float* q1 = &ql[512 + h * 64 + c * 8];
                #pragma unroll
                for (int z = 0; z < 8; ++z) {
                    d0 = fmaf(kf[z], q0[z], d0);
                    d1 = fmaf(kf[z], q1[z], d1);
                }
            }
            S[0][h][jj] = msk0 ? -__builtin_inff() : (d0 + e0[h]);
            S[1][h][jj] = msk1 ? -__builtin_inff() : (d1 + e1[h]);
        }
    }
    __syncthreads();

    // ---- softmax per (row, head) ----
    {
        const int h = t >> 5, l = t & 31;
        #pragma unroll
        for (int r = 0; r < 2; ++r) {
            float m = -__builtin_inff();
            for (int kk = 0; kk < 16; ++kk) m = fmaxf(m, S[r][h][l + 32 * kk]);
            #pragma unroll
            for (int off = 16; off >= 1; off >>= 1) m = fmaxf(m, __shfl_xor(m, off, 32));

            float zsum = 0.f;
            for (int kk = 0; kk < 16; ++kk) {
                const int j = l + 32 * kk;
                const float s = S[r][h][j];
                const float e = (s == -__builtin_inff()) ? 0.f : __expf(s - m);
                S[r][h][j] = e;
                zsum += e;
            }
            #pragma unroll
            for (int off = 16; off >= 1; off >>= 1) zsum += __shfl_xor(zsum, off, 32);

            const float inv = (zsum > 0.f) ? (1.f / zsum) : 0.f;
            for (int kk = 0; kk < 16; ++kk) S[r][h][l + 32 * kk] *= inv;
        }
    }
    __syncthreads();

    // ---- attn mean over heads ----
    for (int jj = t; jj < 512; jj += 256) {
        #pragma unroll
        for (int r = 0; r < 2; ++r) {
            float sum = 0.f;
            #pragma unroll
            for (int h = 0; h < 8; ++h) sum += S[r][h][jj];
            mean_out[(long)(row0 + r) * 512 + jj] = sum * 0.125f;
        }
    }

    // ---- PV ----
    {
        const int h = t >> 5, d0 = (t & 31) * 2;
        float a00 = 0.f, a01 = 0.f, a10 = 0.f, a11 = 0.f;
        const u16* vp = vws + (long)(b * N_) * 512 + h * 64 + d0;
        #pragma unroll 4
        for (int j = 0; j < 512; ++j) {
            const u32 u = *(const u32*)(vp + (long)j * 512);
            const float v0 = __uint_as_float(u << 16);
            const float v1 = __uint_as_float(u & 0xffff0000u);
            const float p0 = S[0][h][j];
            const float p1 = S[1][h][j];
            a00 = fmaf(p0, v0, a00); a01 = fmaf(p0, v1, a01);
            a10 = fmaf(p1, v0, a10); a11 = fmaf(p1, v1, a11);
        }
        *(u32*)&attn_out[(long)row0       * 512 + h * 64 + d0] = pk2(a00, a01);
        *(u32*)&attn_out[(long)(row0 + 1) * 512 + h * 64 + d0] = pk2(a10, a11);
    }
}

// ---------------------------------------------------------------------------
// Fallback fused attention (round-4 proven path) for small ws_size.
// ---------------------------------------------------------------------------
__global__ __launch_bounds__(256) void attn_fused_kernel(
    const float* __restrict__ qws, const u16* __restrict__ kws, const u16* __restrict__ vws,
    const float* __restrict__ ef,
    const float* __restrict__ We1, const float* __restrict__ be1,
    const float* __restrict__ We2, const float* __restrict__ be2,
    const int* __restrict__ bmask, const int* __restrict__ pmask,
    u16* __restrict__ attn_out, float* __restrict__ mean_out)
{
    __shared__ float ql[2 * 512];
    __shared__ float S[2][8][512];
    __shared__ __align__(16) float wf[2632];

    const int t = threadIdx.x;
    const int b = blockIdx.x >> 8;
    const int i0 = (blockIdx.x & 255) * 2;
    const int row0 = b * N_ + i0;

    for (int i = t; i < 2632; i += 256) {
        float v;
        if (i < 2048)      v = We1[i];
        else if (i < 2112) v = be1[i - 2048];
        else if (i < 2624) v = We2[i - 2112];
        else               v = be2[i - 2624];
        wf[i] = v;
    }
    *(float4_t*)&ql[t * 4] = *(const float4_t*)&qws[row0 * 512 + t * 4];

    const int padi0 = pmask[b * N_ + i0];
    const int padi1 = pmask[b * N_ + i0 + 1];
    __syncthreads();

    const float4_t* We1v = (const float4_t*)wf;
    const float4_t* be1v = (const float4_t*)(wf + 2048);
    const float4_t* We2v = (const float4_t*)(wf + 2112);
    const float4_t* be2v = (const float4_t*)(wf + 2624);

    for (int jj = t; jj < 512; jj += 256) {
        const int pj  = pmask[b * N_ + jj];
        const int bm0 = bmask[row0 * 512 + jj];
        const int bm1 = bmask[(row0 + 1) * 512 + jj];
        const bool msk0 = (padi0 | pj | bm0) != 0;
        const bool msk1 = (padi1 | pj | bm1) != 0;

        float x0[32], x1[32];
        {
            const float4_t* p0 = (const float4_t*)(ef + ((long)row0       * 512 + jj) * 32);
            const float4_t* p1 = (const float4_t*)(ef + ((long)(row0 + 1) * 512 + jj) * 32);
            #pragma unroll
            for (int c = 0; c < 8; ++c) {
                float4_t a = p0[c], bb = p1[c];
                #pragma unroll
                for (int z = 0; z < 4; ++z) { x0[c * 4 + z] = a[z]; x1[c * 4 + z] = bb[z]; }
            }
        }

        float e0[8], e1[8];
        {
            float4_t o0a = be2v[0], o0b = be2v[1];
            float4_t o1a = o0a,     o1b = o0b;
            #pragma unroll 1
            for (int o4 = 0; o4 < 16; ++o4) {
                float4_t h0 = be1v[o4], h1 = h0;
                #pragma unroll
                for (int e = 0; e < 32; ++e) {
                    const float4_t w = We1v[e * 16 + o4];
                    const float xe0 = x0[e], xe1 = x1[e];
                    #pragma unroll
                    for (int z = 0; z < 4; ++z) {
                        h0[z] = fmaf(xe0, w[z], h0[z]);
                        h1[z] = fmaf(xe1, w[z], h1[z]);
                    }
                }
                #pragma unroll
                for (int z = 0; z < 4; ++z) {
                    h0[z] = (h0[z] > 0.f) ? h0[z] : expm1f(h0[z]);
                    h1[z] = (h1[z] > 0.f) ? h1[z] : expm1f(h1[z]);
                }
                #pragma unroll
                for (int z = 0; z < 4; ++z) {
                    const int o = o4 * 4 + z;
                    const float4_t wa = We2v[o * 2], wb = We2v[o * 2 + 1];
                    #pragma unroll
                    for (int p = 0; p < 4; ++p) {
                        o0a[p] = fmaf(h0[z], wa[p], o0a[p]);
                        o0b[p] = fmaf(h0[z], wb[p], o0b[p]);
                        o1a[p] = fmaf(h1[z], wa[p], o1a[p]);
                        o1b[p] = fmaf(h1[z], wb[p], o1b[p]);
                    }
                }
            }
            #pragma unroll
            for (int p = 0; p < 4; ++p) {
                e0[p] = o0a[p]; e0[p + 4] = o0b[p];
                e1[p] = o1a[p]; e1[p + 4] = o1b[p];
            }
        }

        const u16* kp = kws + (long)(b * N_ + jj) * 512;
        #pragma unroll
        for (int h = 0; h < 8; ++h) {
            float d0 = 0.f, d1 = 0.f;
            #pragma unroll
            for (int c = 0; c < 8; ++c) {
                uint4v u = *(const uint4v*)(kp + h * 64 + c * 8);
                float kf[8]; unp8(u, kf);
                const float* q0 = &ql[h * 64 + c * 8];
                const float* q1 = &ql[512 + h * 64 + c * 8];
                #pragma unroll
                for (int z = 0; z < 8; ++z) {
                    d0 = fmaf(kf[z], q0[z], d0);
                    d1 = fmaf(kf[z], q1[z], d1);
                }
            }
            S[0][h][jj] = msk0 ? -__builtin_inff() : (d0 + e0[h]);
            S[1][h][jj] = msk1 ? -__builtin_inff() : (d1 + e1[h]);
        }
    }
    __syncthreads();

    {
        const int h = t >> 5, l = t & 31;
        #pragma unroll
        for (int r = 0; r < 2; ++r) {
            float m = -__builtin_inff();
            for (int kk = 0; kk < 16; ++kk) m = fmaxf(m, S[r][h][l + 32 * kk]);
            #pragma unroll
            for (int off = 16; off >= 1; off >>= 1) m = fmaxf(m, __shfl_xor(m, off, 32));

            float zsum = 0.f;
            for (int kk = 0; kk < 16; ++kk) {
                const int j = l + 32 * kk;
                const float s = S[r][h][j];
                const float e = (s == -__builtin_inff()) ? 0.f : __expf(s - m);
                S[r][h][j] = e;
                zsum += e;
            }
            #pragma unroll
            for (int off = 16; off >= 1; off >>= 1) zsum += __shfl_xor(zsum, off, 32);

            const float inv = (zsum > 0.f) ? (1.f / zsum) : 0.f;
            for (int kk = 0; kk < 16; ++kk) S[r][h][l + 32 * kk] *= inv;
        }
    }
    __syncthreads();

    for (int jj = t; jj < 512; jj += 256) {
        #pragma unroll
        for (int r = 0; r < 2; ++r) {
            float sum = 0.f;
            #pragma unroll
            for (int h = 0; h < 8; ++h) sum += S[r][h][jj];
            mean_out[(long)(row0 + r) * 512 + jj] = sum * 0.125f;
        }
    }

    {
        const int h = t >> 5, d0 = (t & 31) * 2;
        float a00 = 0.f, a01 = 0.f, a10 = 0.f, a11 = 0.f;
        const u16* vp = vws + (long)(b * N_) * 512 + h * 64 + d0;
        #pragma unroll 4
        for (int j = 0; j < 512; ++j) {
            const u32 u = *(const u32*)(vp + (long)j * 512);
            const float v0 = __uint_as_float(u << 16);
            const float v1 = __uint_as_float(u & 0xffff0000u);
            const float p0 = S[0][h][j];
            const float p1 = S[1][h][j];
            a00 = fmaf(p0, v0, a00); a01 = fmaf(p0, v1, a01);
            a10 = fmaf(p1, v0, a10); a11 = fmaf(p1, v1, a11);
        }
        *(u32*)&attn_out[(long)row0       * 512 + h * 64 + d0] = pk2(a00, a01);
        *(u32*)&attn_out[(long)(row0 + 1) * 512 + h * 64 + d0] = pk2(a10, a11);
    }
}

// ---------------------------------------------------------------------------
extern "C" void kernel_launch(void* const* d_in, const int* in_sizes, int n_in,
                              void* d_out, int out_size, void* d_ws, size_t ws_size,
                              hipStream_t stream) {
    const float* x   = (const float*)d_in[0];
    const int*   ct  = (const int*)d_in[1];
    const float* ef  = (const float*)d_in[2];
    const int*   bm  = (const int*)d_in[3];
    const int*   pm  = (const int*)d_in[4];
    const float* Wq  = (const float*)d_in[5];  const float* bq = (const float*)d_in[6];
    const float* Wk  = (const float*)d_in[7];  const float* bk = (const float*)d_in[8];
    const float* Wv  = (const float*)d_in[9];  const float* bv = (const float*)d_in[10];
    const float* Wo  = (const float*)d_in[11]; const float* bo = (const float*)d_in[12];
    const float* We1 = (const float*)d_in[13]; const float* be1 = (const float*)d_in[14];
    const float* We2 = (const float*)d_in[15]; const float* be2 = (const float*)d_in[16];
    const float* ctk = (const float*)d_in[17];
    // d_in[18] = ct_bias_emb: constant along softmax axis -> cancels; unused.

    char* ws = (char*)d_ws;
    float* qws  = (float*)ws;                    //  8,388,608 B (fp32, pre-scaled)
    u16*   kws  = (u16*)(ws + 8388608);          //  4,194,304 B (bf16, +ct_key)
    u16*   vws  = (u16*)(ws + 12582912);         //  4,194,304 B
    u16*   aout = (u16*)(ws + 16777216);         //  4,194,304 B (attn out, bf16)
    u16*   ebws = (u16*)(ws + 20971520);         // 33,554,432 B (edge bias, bf16)
    const size_t WS_BIG = 54525952;

    float* out0 = (float*)d_out;        // (B,N,HID) fp32
    float* out1 = out0 + 2097152;       // (B,N,N)  fp32 attn mean

    gemm_kernel<<<dim3(32, 24), 256, 0, stream>>>(x, nullptr, Wq, Wk, Wv, bq, bk, bv,
                                                  qws, kws, vws, out0, ctk, ct, 0);
    if (ws_size >= WS_BIG) {
        edge_kernel<<<8192, 256, 0, stream>>>(ef, We1, be1, We2, be2, ebws);
        attn_kernel<<<2048, 256, 0, stream>>>(qws, kws, vws, ebws, bm, pm, aout, out1);
    } else {
        attn_fused_kernel<<<2048, 256, 0, stream>>>(qws, kws, vws, ef, We1, be1, We2, be2,
                                                    bm, pm, aout, out1);
    }
    gemm_kernel<<<dim3(32, 8), 256, 0, stream>>>(nullptr, aout, Wo, Wo, Wo, bo, bo, bo,
                                                 qws, kws, vws, out0, ctk, ct, 1);
}